// Round 3
// baseline (649.933 us; speedup 1.0000x reference)
//
#include <hip/hip_runtime.h>
#include <hip/hip_bf16.h>

#define NN 50000
#define NE 800000
#define BN_EPS 1e-5f

// ---------------- utility: zero ints ----------------
__global__ void zero_k(int* __restrict__ p, int n) {
    int i = blockIdx.x * 256 + threadIdx.x;
    if (i < n) p[i] = 0;
}

// ---------------- CSR build ----------------
__global__ void hist_k(const int* __restrict__ dst, int* __restrict__ deg) {
    int e = blockIdx.x * 256 + threadIdx.x;
    if (e < NE) atomicAdd(&deg[dst[e]], 1);
}

__global__ void scan_k(const int* __restrict__ deg, int* __restrict__ off,
                       int* __restrict__ cur) {
    const int CH = (NN + 255) / 256;  // 196
    int t = threadIdx.x;
    int base = t * CH;
    int s = 0;
    for (int i = 0; i < CH; i++) {
        int idx = base + i;
        if (idx < NN) s += deg[idx];
    }
    __shared__ int part[256];
    part[t] = s;
    __syncthreads();
    for (int d = 1; d < 256; d <<= 1) {
        int v = (t >= d) ? part[t - d] : 0;
        __syncthreads();
        part[t] += v;
        __syncthreads();
    }
    int ex = (t == 0) ? 0 : part[t - 1];
    for (int i = 0; i < CH; i++) {
        int idx = base + i;
        if (idx < NN) {
            off[idx] = ex;
            cur[idx] = ex;
            ex += deg[idx];
        }
    }
    if (t == 255) off[NN] = part[255];
}

__global__ void scatter_k(const int* __restrict__ src, const int* __restrict__ dst,
                          int* __restrict__ cur, int* __restrict__ adj) {
    int e = blockIdx.x * 256 + threadIdx.x;
    if (e < NE) {
        int d = dst[e];
        int p = atomicAdd(&cur[d], 1);
        adj[p] = src[e];
    }
}

// ---------------- aggregation: AGG[i] = X[i] + sum_{j->i} X[j]  (fp32) ---------
// one wave per node, lane = feature (64 feats)
__global__ void gather_k(const float* __restrict__ X, int ldx,
                         const int* __restrict__ off, const int* __restrict__ adj,
                         float* __restrict__ AGG) {
    int node = blockIdx.x * 4 + (threadIdx.x >> 6);
    int lane = threadIdx.x & 63;
    if (node >= NN) return;
    float acc = X[(size_t)node * ldx + lane];
    int s = off[node], e = off[node + 1];
    for (int p = s; p < e; p++) {
        int j = adj[p];
        acc += X[(size_t)j * ldx + lane];
    }
    AGG[(size_t)node * 64 + lane] = acc;
}

// ---------------- GEMM (N x 64) @ (64 x 64) + bias, fp32, + BN stats ----------
// block 256 = 16x16 threads; block tile 64 rows x 64 cols; 4x4 micro-tile/thread
__global__ void gemm64_k(const float* __restrict__ A,
                         const float* __restrict__ W,    // 64x64 row-major
                         const float* __restrict__ bias,
                         float* __restrict__ T,
                         float* __restrict__ sums) {  // [64] sum, [64] sumsq
    __shared__ float As[64 * 72];   // [k][r], pad 72
    __shared__ float Ws[64 * 64];   // [k][n]
    __shared__ float lsum[64], lssq[64];
    int tid = threadIdx.x;
    int rowbase = blockIdx.x * 64;
    for (int i = tid; i < 64 * 64; i += 256) {
        int r = i >> 6, k = i & 63;
        int row = rowbase + r;
        if (row >= NN) row = NN - 1;
        As[k * 72 + r] = A[row * 64 + k];
        Ws[i] = W[i];
    }
    if (tid < 64) { lsum[tid] = 0.f; lssq[tid] = 0.f; }
    __syncthreads();

    int ty = tid >> 4, tx = tid & 15;
    float acc[4][4] = {};
    for (int k = 0; k < 64; k++) {
        float a[4], wv[4];
        #pragma unroll
        for (int i = 0; i < 4; i++) a[i] = As[k * 72 + ty * 4 + i];
        #pragma unroll
        for (int j = 0; j < 4; j++) wv[j] = Ws[k * 64 + tx * 4 + j];
        #pragma unroll
        for (int i = 0; i < 4; i++)
            #pragma unroll
            for (int j = 0; j < 4; j++) acc[i][j] += a[i] * wv[j];
    }

    #pragma unroll
    for (int j = 0; j < 4; j++) {
        int c = tx * 4 + j;
        float bv = bias[c];
        float ps = 0.f, pq = 0.f;
        #pragma unroll
        for (int i = 0; i < 4; i++) {
            int row = rowbase + ty * 4 + i;
            if (row < NN) {
                float v = acc[i][j] + bv;
                T[row * 64 + c] = v;
                ps += v;
                pq += v * v;
            }
        }
        atomicAdd(&lsum[c], ps);
        atomicAdd(&lssq[c], pq);
    }
    __syncthreads();
    if (tid < 64) {
        atomicAdd(&sums[tid], lsum[tid]);
        atomicAdd(&sums[64 + tid], lssq[tid]);
    }
}

// ---------------- BN finalize + apply + ReLU (fp32) ----------------
__global__ void bn_k(const float* __restrict__ T, const float* __restrict__ sums,
                     const float* __restrict__ g,
                     const float* __restrict__ be,
                     float* __restrict__ H, int ldh) {
    __shared__ float sc[64], sh[64];
    int tid = threadIdx.x;
    if (tid < 64) {
        float m = sums[tid] * (1.0f / NN);
        float var = sums[64 + tid] * (1.0f / NN) - m * m;
        if (var < 0.f) var = 0.f;
        float s = g[tid] * rsqrtf(var + BN_EPS);
        sc[tid] = s;
        sh[tid] = be[tid] - m * s;
    }
    __syncthreads();
    int i = blockIdx.x * 256 + tid;
    if (i < NN * 64) {
        int row = i >> 6, f = i & 63;
        float v = T[i] * sc[f] + sh[f];
        H[row * ldh + f] = v > 0.f ? v : 0.f;
    }
}

// ---------------- final GEMM: (N x 128) @ (128 x 64) + bias -> fp32 out -------
__global__ void gemmfin_k(const float* __restrict__ A,   // N x 128 fp32
                          const float* __restrict__ W,   // 128x64 row-major
                          const float* __restrict__ bias,
                          float* __restrict__ O) {
    __shared__ float As[128 * 72];  // [k][r], r<64
    __shared__ float Ws[128 * 64];  // [k][n]
    int tid = threadIdx.x;
    int rowbase = blockIdx.x * 64;
    for (int i = tid; i < 128 * 64; i += 256) {
        int r = i >> 7, k = i & 127;
        int row = rowbase + r;
        if (row >= NN) row = NN - 1;
        As[k * 72 + r] = A[row * 128 + k];
        Ws[i] = W[i];
    }
    __syncthreads();

    int ty = tid >> 4, tx = tid & 15;
    float acc[4][4] = {};
    for (int k = 0; k < 128; k++) {
        float a[4], wv[4];
        #pragma unroll
        for (int i = 0; i < 4; i++) a[i] = As[k * 72 + ty * 4 + i];
        #pragma unroll
        for (int j = 0; j < 4; j++) wv[j] = Ws[k * 64 + tx * 4 + j];
        #pragma unroll
        for (int i = 0; i < 4; i++)
            #pragma unroll
            for (int j = 0; j < 4; j++) acc[i][j] += a[i] * wv[j];
    }

    #pragma unroll
    for (int j = 0; j < 4; j++) {
        int c = tx * 4 + j;
        float bv = bias[c];
        #pragma unroll
        for (int i = 0; i < 4; i++) {
            int row = rowbase + ty * 4 + i;
            if (row < NN) O[row * 64 + c] = acc[i][j] + bv;
        }
    }
}

// ---------------- launch ----------------
extern "C" void kernel_launch(void* const* d_in, const int* in_sizes, int n_in,
                              void* d_out, int out_size, void* d_ws, size_t ws_size,
                              hipStream_t stream) {
    const float* x   = (const float*)d_in[0];
    const int*   ei  = (const int*)d_in[1];
    const float* w0a = (const float*)d_in[2];
    const float* b0a = (const float*)d_in[3];
    const float* g0a = (const float*)d_in[4];
    const float* be0a= (const float*)d_in[5];
    const float* w0b = (const float*)d_in[6];
    const float* b0b = (const float*)d_in[7];
    const float* g0b = (const float*)d_in[8];
    const float* be0b= (const float*)d_in[9];
    const float* w1a = (const float*)d_in[10];
    const float* b1a = (const float*)d_in[11];
    const float* g1a = (const float*)d_in[12];
    const float* be1a= (const float*)d_in[13];
    const float* w1b = (const float*)d_in[14];
    const float* b1b = (const float*)d_in[15];
    const float* g1b = (const float*)d_in[16];
    const float* be1b= (const float*)d_in[17];
    const float* lw  = (const float*)d_in[18];
    const float* lb  = (const float*)d_in[19];
    float* out = (float*)d_out;
    (void)in_sizes; (void)n_in; (void)out_size; (void)ws_size;

    char* wsb = (char*)d_ws;
    size_t o = 0;
    auto alloc = [&](size_t bytes) -> char* {
        char* p = wsb + o;
        o += (bytes + 255) & ~(size_t)255;
        return p;
    };
    int* deg = (int*)alloc(NN * 4);           // zeroed below
    float* sums = (float*)alloc(512 * 4);     // zeroed below (4 sets of 128)
    int* off = (int*)alloc((NN + 1) * 4);
    int* cur = (int*)alloc(NN * 4);
    int* adj = (int*)alloc(NE * 4);
    float* AGG = (float*)alloc((size_t)NN * 64 * 4);
    float* T   = (float*)alloc((size_t)NN * 64 * 4);
    float* Ht  = (float*)alloc((size_t)NN * 64 * 4);
    float* HC  = (float*)alloc((size_t)NN * 128 * 4);

    const int* src = ei;
    const int* dst = ei + NE;

    // deg chunk padded to 200192 B + sums 2048 B -> 202240 B = 50560 ints
    zero_k<<<198, 256, 0, stream>>>((int*)d_ws, 50560);
    hist_k<<<NE / 256, 256, 0, stream>>>(dst, deg);
    scan_k<<<1, 256, 0, stream>>>(deg, off, cur);
    scatter_k<<<NE / 256, 256, 0, stream>>>(src, dst, cur, adj);

    const int ggrid = NN / 4;                  // 12500 (wave per node)
    const int mgrid = (NN + 63) / 64;          // 782
    const int agrid = (NN * 64 + 255) / 256;   // 12500

    // ---- layer 0 ----
    gather_k<<<ggrid, 256, 0, stream>>>(x, 64, off, adj, AGG);
    gemm64_k<<<mgrid, 256, 0, stream>>>(AGG, w0a, b0a, T, sums + 0);
    bn_k<<<agrid, 256, 0, stream>>>(T, sums + 0, g0a, be0a, Ht, 64);
    gemm64_k<<<mgrid, 256, 0, stream>>>(Ht, w0b, b0b, T, sums + 128);
    bn_k<<<agrid, 256, 0, stream>>>(T, sums + 128, g0b, be0b, HC, 128);       // h1

    // ---- layer 1 ----
    gather_k<<<ggrid, 256, 0, stream>>>(HC, 128, off, adj, AGG);
    gemm64_k<<<mgrid, 256, 0, stream>>>(AGG, w1a, b1a, T, sums + 256);
    bn_k<<<agrid, 256, 0, stream>>>(T, sums + 256, g1a, be1a, Ht, 64);
    gemm64_k<<<mgrid, 256, 0, stream>>>(Ht, w1b, b1b, T, sums + 384);
    bn_k<<<agrid, 256, 0, stream>>>(T, sums + 384, g1b, be1b, HC + 64, 128);  // h2

    // ---- JK cat + final linear ----
    gemmfin_k<<<mgrid, 256, 0, stream>>>(HC, lw, lb, out);
}

// Round 4
// 502.100 us; speedup vs baseline: 1.2944x; 1.2944x over previous
//
#include <hip/hip_runtime.h>
#include <hip/hip_bf16.h>

#define NN 50000
#define NE 800000
#define BN_EPS 1e-5f
#define SCAN_BLKS 196  // ceil(50000/256)

// ---------------- utility: zero ints ----------------
__global__ void zero_k(int* __restrict__ p, int n) {
    int i = blockIdx.x * 256 + threadIdx.x;
    if (i < n) p[i] = 0;
}

// ---------------- CSR build ----------------
__global__ void hist_k(const int* __restrict__ dst, int* __restrict__ deg) {
    int e = blockIdx.x * 256 + threadIdx.x;
    if (e < NE) atomicAdd(&deg[dst[e]], 1);
}

// per-block sums of deg
__global__ void blocksum_k(const int* __restrict__ deg, int* __restrict__ part) {
    __shared__ int sd[256];
    int t = threadIdx.x;
    int idx = blockIdx.x * 256 + t;
    sd[t] = idx < NN ? deg[idx] : 0;
    __syncthreads();
    for (int d = 128; d > 0; d >>= 1) {
        if (t < d) sd[t] += sd[t + d];
        __syncthreads();
    }
    if (t == 0) part[blockIdx.x] = sd[0];
}

// scan the 196 block partials -> exclusive block offsets
__global__ void scanpart_k(const int* __restrict__ part, int* __restrict__ blkoff,
                           int* __restrict__ off) {
    __shared__ int s[256];
    int t = threadIdx.x;
    int v = t < SCAN_BLKS ? part[t] : 0;
    s[t] = v;
    __syncthreads();
    for (int d = 1; d < 256; d <<= 1) {
        int u = (t >= d) ? s[t - d] : 0;
        __syncthreads();
        s[t] += u;
        __syncthreads();
    }
    if (t < SCAN_BLKS) blkoff[t] = s[t] - v;
    if (t == 0) off[NN] = NE;  // sum of degrees is always E
}

// intra-block exclusive scan + block offset -> off/cur
__global__ void applyscan_k(const int* __restrict__ deg, const int* __restrict__ blkoff,
                            int* __restrict__ off, int* __restrict__ cur) {
    __shared__ int s[256];
    int t = threadIdx.x;
    int idx = blockIdx.x * 256 + t;
    int v = idx < NN ? deg[idx] : 0;
    s[t] = v;
    __syncthreads();
    for (int d = 1; d < 256; d <<= 1) {
        int u = (t >= d) ? s[t - d] : 0;
        __syncthreads();
        s[t] += u;
        __syncthreads();
    }
    int ex = blkoff[blockIdx.x] + s[t] - v;
    if (idx < NN) {
        off[idx] = ex;
        cur[idx] = ex;
    }
}

__global__ void scatter_k(const int* __restrict__ src, const int* __restrict__ dst,
                          int* __restrict__ cur, int* __restrict__ adj) {
    int e = blockIdx.x * 256 + threadIdx.x;
    if (e < NE) {
        int d = dst[e];
        int p = atomicAdd(&cur[d], 1);
        adj[p] = src[e];
    }
}

// ---------------- aggregation: AGG[i] = X[i] + sum_{j->i} X[j]  (fp32) ---------
// one wave per node, lane = feature (64 feats)
__global__ void gather_k(const float* __restrict__ X, int ldx,
                         const int* __restrict__ off, const int* __restrict__ adj,
                         float* __restrict__ AGG) {
    int node = blockIdx.x * 4 + (threadIdx.x >> 6);
    int lane = threadIdx.x & 63;
    if (node >= NN) return;
    float acc = X[(size_t)node * ldx + lane];
    int s = off[node], e = off[node + 1];
    for (int p = s; p < e; p++) {
        int j = adj[p];
        acc += X[(size_t)j * ldx + lane];
    }
    AGG[(size_t)node * 64 + lane] = acc;
}

// ---------------- GEMM (N x 64) @ (64 x 64) + bias, fp32, + BN stats ----------
// block 256 = 16x16 threads; block tile 64 rows x 64 cols; 4x4 micro-tile/thread
__global__ void gemm64_k(const float* __restrict__ A,
                         const float* __restrict__ W,    // 64x64 row-major
                         const float* __restrict__ bias,
                         float* __restrict__ T,
                         float* __restrict__ sums) {  // [64] sum, [64] sumsq
    __shared__ float As[64 * 72];   // [k][r], pad 72
    __shared__ float Ws[64 * 64];   // [k][n]
    __shared__ float lsum[64], lssq[64];
    int tid = threadIdx.x;
    int rowbase = blockIdx.x * 64;
    for (int i = tid; i < 64 * 64; i += 256) {
        int r = i >> 6, k = i & 63;
        int row = rowbase + r;
        if (row >= NN) row = NN - 1;
        As[k * 72 + r] = A[row * 64 + k];
        Ws[i] = W[i];
    }
    if (tid < 64) { lsum[tid] = 0.f; lssq[tid] = 0.f; }
    __syncthreads();

    int ty = tid >> 4, tx = tid & 15;
    float acc[4][4] = {};
    for (int k = 0; k < 64; k++) {
        float a[4], wv[4];
        #pragma unroll
        for (int i = 0; i < 4; i++) a[i] = As[k * 72 + ty * 4 + i];
        #pragma unroll
        for (int j = 0; j < 4; j++) wv[j] = Ws[k * 64 + tx * 4 + j];
        #pragma unroll
        for (int i = 0; i < 4; i++)
            #pragma unroll
            for (int j = 0; j < 4; j++) acc[i][j] += a[i] * wv[j];
    }

    #pragma unroll
    for (int j = 0; j < 4; j++) {
        int c = tx * 4 + j;
        float bv = bias[c];
        float ps = 0.f, pq = 0.f;
        #pragma unroll
        for (int i = 0; i < 4; i++) {
            int row = rowbase + ty * 4 + i;
            if (row < NN) {
                float v = acc[i][j] + bv;
                T[row * 64 + c] = v;
                ps += v;
                pq += v * v;
            }
        }
        atomicAdd(&lsum[c], ps);
        atomicAdd(&lssq[c], pq);
    }
    __syncthreads();
    if (tid < 64) {
        atomicAdd(&sums[tid], lsum[tid]);
        atomicAdd(&sums[64 + tid], lssq[tid]);
    }
}

// ---- GEMM with fused BN+ReLU on the input: A = relu(Tin*sc + sh), then @W ----
__global__ void gemm64bn_k(const float* __restrict__ Tin,
                           const float* __restrict__ stats,  // [64] sum,[64] sumsq of Tin
                           const float* __restrict__ g,
                           const float* __restrict__ be,
                           const float* __restrict__ W,      // 64x64 row-major
                           const float* __restrict__ bias,
                           float* __restrict__ T,
                           float* __restrict__ sums) {
    __shared__ float As[64 * 72];
    __shared__ float Ws[64 * 64];
    __shared__ float sc[64], sh[64];
    __shared__ float lsum[64], lssq[64];
    int tid = threadIdx.x;
    int rowbase = blockIdx.x * 64;
    if (tid < 64) {
        float m = stats[tid] * (1.0f / NN);
        float var = stats[64 + tid] * (1.0f / NN) - m * m;
        if (var < 0.f) var = 0.f;
        float s = g[tid] * rsqrtf(var + BN_EPS);
        sc[tid] = s;
        sh[tid] = be[tid] - m * s;
        lsum[tid] = 0.f;
        lssq[tid] = 0.f;
    }
    __syncthreads();
    for (int i = tid; i < 64 * 64; i += 256) {
        int r = i >> 6, k = i & 63;
        int row = rowbase + r;
        if (row >= NN) row = NN - 1;
        float v = Tin[row * 64 + k] * sc[k] + sh[k];
        As[k * 72 + r] = v > 0.f ? v : 0.f;
        Ws[i] = W[i];
    }
    __syncthreads();

    int ty = tid >> 4, tx = tid & 15;
    float acc[4][4] = {};
    for (int k = 0; k < 64; k++) {
        float a[4], wv[4];
        #pragma unroll
        for (int i = 0; i < 4; i++) a[i] = As[k * 72 + ty * 4 + i];
        #pragma unroll
        for (int j = 0; j < 4; j++) wv[j] = Ws[k * 64 + tx * 4 + j];
        #pragma unroll
        for (int i = 0; i < 4; i++)
            #pragma unroll
            for (int j = 0; j < 4; j++) acc[i][j] += a[i] * wv[j];
    }

    #pragma unroll
    for (int j = 0; j < 4; j++) {
        int c = tx * 4 + j;
        float bv = bias[c];
        float ps = 0.f, pq = 0.f;
        #pragma unroll
        for (int i = 0; i < 4; i++) {
            int row = rowbase + ty * 4 + i;
            if (row < NN) {
                float v = acc[i][j] + bv;
                T[row * 64 + c] = v;
                ps += v;
                pq += v * v;
            }
        }
        atomicAdd(&lsum[c], ps);
        atomicAdd(&lssq[c], pq);
    }
    __syncthreads();
    if (tid < 64) {
        atomicAdd(&sums[tid], lsum[tid]);
        atomicAdd(&sums[64 + tid], lssq[tid]);
    }
}

// ---------------- BN finalize + apply + ReLU (fp32), strided output ------------
__global__ void bn_k(const float* __restrict__ T, const float* __restrict__ sums,
                     const float* __restrict__ g,
                     const float* __restrict__ be,
                     float* __restrict__ H, int ldh) {
    __shared__ float sc[64], sh[64];
    int tid = threadIdx.x;
    if (tid < 64) {
        float m = sums[tid] * (1.0f / NN);
        float var = sums[64 + tid] * (1.0f / NN) - m * m;
        if (var < 0.f) var = 0.f;
        float s = g[tid] * rsqrtf(var + BN_EPS);
        sc[tid] = s;
        sh[tid] = be[tid] - m * s;
    }
    __syncthreads();
    int i = blockIdx.x * 256 + tid;
    if (i < NN * 64) {
        int row = i >> 6, f = i & 63;
        float v = T[i] * sc[f] + sh[f];
        H[row * ldh + f] = v > 0.f ? v : 0.f;
    }
}

// ---------------- final GEMM: (N x 128) @ (128 x 64) + bias -> fp32 out -------
__global__ void gemmfin_k(const float* __restrict__ A,   // N x 128 fp32
                          const float* __restrict__ W,   // 128x64 row-major
                          const float* __restrict__ bias,
                          float* __restrict__ O) {
    __shared__ float As[128 * 72];
    __shared__ float Ws[128 * 64];
    int tid = threadIdx.x;
    int rowbase = blockIdx.x * 64;
    for (int i = tid; i < 128 * 64; i += 256) {
        int r = i >> 7, k = i & 127;
        int row = rowbase + r;
        if (row >= NN) row = NN - 1;
        As[k * 72 + r] = A[row * 128 + k];
        Ws[i] = W[i];
    }
    __syncthreads();

    int ty = tid >> 4, tx = tid & 15;
    float acc[4][4] = {};
    for (int k = 0; k < 128; k++) {
        float a[4], wv[4];
        #pragma unroll
        for (int i = 0; i < 4; i++) a[i] = As[k * 72 + ty * 4 + i];
        #pragma unroll
        for (int j = 0; j < 4; j++) wv[j] = Ws[k * 64 + tx * 4 + j];
        #pragma unroll
        for (int i = 0; i < 4; i++)
            #pragma unroll
            for (int j = 0; j < 4; j++) acc[i][j] += a[i] * wv[j];
    }

    #pragma unroll
    for (int j = 0; j < 4; j++) {
        int c = tx * 4 + j;
        float bv = bias[c];
        #pragma unroll
        for (int i = 0; i < 4; i++) {
            int row = rowbase + ty * 4 + i;
            if (row < NN) O[row * 64 + c] = acc[i][j] + bv;
        }
    }
}

// ---------------- launch ----------------
extern "C" void kernel_launch(void* const* d_in, const int* in_sizes, int n_in,
                              void* d_out, int out_size, void* d_ws, size_t ws_size,
                              hipStream_t stream) {
    const float* x   = (const float*)d_in[0];
    const int*   ei  = (const int*)d_in[1];
    const float* w0a = (const float*)d_in[2];
    const float* b0a = (const float*)d_in[3];
    const float* g0a = (const float*)d_in[4];
    const float* be0a= (const float*)d_in[5];
    const float* w0b = (const float*)d_in[6];
    const float* b0b = (const float*)d_in[7];
    const float* g0b = (const float*)d_in[8];
    const float* be0b= (const float*)d_in[9];
    const float* w1a = (const float*)d_in[10];
    const float* b1a = (const float*)d_in[11];
    const float* g1a = (const float*)d_in[12];
    const float* be1a= (const float*)d_in[13];
    const float* w1b = (const float*)d_in[14];
    const float* b1b = (const float*)d_in[15];
    const float* g1b = (const float*)d_in[16];
    const float* be1b= (const float*)d_in[17];
    const float* lw  = (const float*)d_in[18];
    const float* lb  = (const float*)d_in[19];
    float* out = (float*)d_out;
    (void)in_sizes; (void)n_in; (void)out_size; (void)ws_size;

    char* wsb = (char*)d_ws;
    size_t o = 0;
    auto alloc = [&](size_t bytes) -> char* {
        char* p = wsb + o;
        o += (bytes + 255) & ~(size_t)255;
        return p;
    };
    int* deg = (int*)alloc(NN * 4);           // zeroed below
    float* sums = (float*)alloc(512 * 4);     // zeroed below (4 sets of 128)
    int* part = (int*)alloc(SCAN_BLKS * 4);
    int* blkoff = (int*)alloc(SCAN_BLKS * 4);
    int* off = (int*)alloc((NN + 1) * 4);
    int* cur = (int*)alloc(NN * 4);
    int* adj = (int*)alloc(NE * 4);
    float* AGG = (float*)alloc((size_t)NN * 64 * 4);
    float* T   = (float*)alloc((size_t)NN * 64 * 4);
    float* T2  = (float*)alloc((size_t)NN * 64 * 4);
    float* HC  = (float*)alloc((size_t)NN * 128 * 4);

    const int* src = ei;
    const int* dst = ei + NE;

    // zero deg (padded to 200192 B) + sums (2048 B) = 50560 ints
    zero_k<<<198, 256, 0, stream>>>((int*)d_ws, 50560);
    hist_k<<<NE / 256, 256, 0, stream>>>(dst, deg);
    blocksum_k<<<SCAN_BLKS, 256, 0, stream>>>(deg, part);
    scanpart_k<<<1, 256, 0, stream>>>(part, blkoff, off);
    applyscan_k<<<SCAN_BLKS, 256, 0, stream>>>(deg, blkoff, off, cur);
    scatter_k<<<NE / 256, 256, 0, stream>>>(src, dst, cur, adj);

    const int ggrid = NN / 4;                  // 12500 (wave per node)
    const int mgrid = (NN + 63) / 64;          // 782
    const int agrid = (NN * 64 + 255) / 256;   // 12500

    // ---- layer 0 ----
    gather_k<<<ggrid, 256, 0, stream>>>(x, 64, off, adj, AGG);
    gemm64_k<<<mgrid, 256, 0, stream>>>(AGG, w0a, b0a, T, sums + 0);
    gemm64bn_k<<<mgrid, 256, 0, stream>>>(T, sums + 0, g0a, be0a, w0b, b0b, T2, sums + 128);
    bn_k<<<agrid, 256, 0, stream>>>(T2, sums + 128, g0b, be0b, HC, 128);      // h1

    // ---- layer 1 ----
    gather_k<<<ggrid, 256, 0, stream>>>(HC, 128, off, adj, AGG);
    gemm64_k<<<mgrid, 256, 0, stream>>>(AGG, w1a, b1a, T, sums + 256);
    gemm64bn_k<<<mgrid, 256, 0, stream>>>(T, sums + 256, g1a, be1a, w1b, b1b, T2, sums + 384);
    bn_k<<<agrid, 256, 0, stream>>>(T2, sums + 384, g1b, be1b, HC + 64, 128); // h2

    // ---- JK cat + final linear ----
    gemmfin_k<<<mgrid, 256, 0, stream>>>(HC, lw, lb, out);
}

// Round 5
// 420.721 us; speedup vs baseline: 1.5448x; 1.1934x over previous
//
#include <hip/hip_runtime.h>
#include <hip/hip_bf16.h>

#define NN 50000
#define NE 800000
#define BN_EPS 1e-5f
#define SCAN_BLKS 196  // ceil(50000/256)

typedef __attribute__((ext_vector_type(4))) float f32x4;

// ---------------- utility: zero ints ----------------
__global__ void zero_k(int* __restrict__ p, int n) {
    int i = blockIdx.x * 256 + threadIdx.x;
    if (i < n) p[i] = 0;
}

// ---------------- CSR build ----------------
__global__ void hist_k(const int* __restrict__ dst, int* __restrict__ deg) {
    int e = blockIdx.x * 256 + threadIdx.x;
    if (e < NE) atomicAdd(&deg[dst[e]], 1);
}

// per-block sums of deg
__global__ void blocksum_k(const int* __restrict__ deg, int* __restrict__ part) {
    __shared__ int sd[256];
    int t = threadIdx.x;
    int idx = blockIdx.x * 256 + t;
    sd[t] = idx < NN ? deg[idx] : 0;
    __syncthreads();
    for (int d = 128; d > 0; d >>= 1) {
        if (t < d) sd[t] += sd[t + d];
        __syncthreads();
    }
    if (t == 0) part[blockIdx.x] = sd[0];
}

// scan the 196 block partials -> exclusive block offsets
__global__ void scanpart_k(const int* __restrict__ part, int* __restrict__ blkoff,
                           int* __restrict__ off) {
    __shared__ int s[256];
    int t = threadIdx.x;
    int v = t < SCAN_BLKS ? part[t] : 0;
    s[t] = v;
    __syncthreads();
    for (int d = 1; d < 256; d <<= 1) {
        int u = (t >= d) ? s[t - d] : 0;
        __syncthreads();
        s[t] += u;
        __syncthreads();
    }
    if (t < SCAN_BLKS) blkoff[t] = s[t] - v;
    if (t == 0) off[NN] = NE;  // sum of degrees is always E
}

// intra-block exclusive scan + block offset -> off/cur
__global__ void applyscan_k(const int* __restrict__ deg, const int* __restrict__ blkoff,
                            int* __restrict__ off, int* __restrict__ cur) {
    __shared__ int s[256];
    int t = threadIdx.x;
    int idx = blockIdx.x * 256 + t;
    int v = idx < NN ? deg[idx] : 0;
    s[t] = v;
    __syncthreads();
    for (int d = 1; d < 256; d <<= 1) {
        int u = (t >= d) ? s[t - d] : 0;
        __syncthreads();
        s[t] += u;
        __syncthreads();
    }
    int ex = blkoff[blockIdx.x] + s[t] - v;
    if (idx < NN) {
        off[idx] = ex;
        cur[idx] = ex;
    }
}

__global__ void scatter_k(const int* __restrict__ src, const int* __restrict__ dst,
                          int* __restrict__ cur, int* __restrict__ adj) {
    int e = blockIdx.x * 256 + threadIdx.x;
    if (e < NE) {
        int d = dst[e];
        int p = atomicAdd(&cur[d], 1);
        adj[p] = src[e];
    }
}

// ---------------- aggregation: AGG[i] = X[i] + sum_{j->i} X[j]  (fp32) ---------
// one wave per node, lane = feature (64 feats); 8-deep load pipelining
__global__ void gather_k(const float* __restrict__ X, int ldx,
                         const int* __restrict__ off, const int* __restrict__ adj,
                         float* __restrict__ AGG) {
    int node = blockIdx.x * 4 + (threadIdx.x >> 6);
    int lane = threadIdx.x & 63;
    if (node >= NN) return;
    float acc = X[(size_t)node * ldx + lane];
    int s = off[node], e = off[node + 1];
    int p = s;
    for (; p + 8 <= e; p += 8) {
        int j0 = adj[p + 0], j1 = adj[p + 1], j2 = adj[p + 2], j3 = adj[p + 3];
        int j4 = adj[p + 4], j5 = adj[p + 5], j6 = adj[p + 6], j7 = adj[p + 7];
        float v0 = X[(size_t)j0 * ldx + lane];
        float v1 = X[(size_t)j1 * ldx + lane];
        float v2 = X[(size_t)j2 * ldx + lane];
        float v3 = X[(size_t)j3 * ldx + lane];
        float v4 = X[(size_t)j4 * ldx + lane];
        float v5 = X[(size_t)j5 * ldx + lane];
        float v6 = X[(size_t)j6 * ldx + lane];
        float v7 = X[(size_t)j7 * ldx + lane];
        acc += ((v0 + v1) + (v2 + v3)) + ((v4 + v5) + (v6 + v7));
    }
    if (p + 4 <= e) {
        int j0 = adj[p + 0], j1 = adj[p + 1], j2 = adj[p + 2], j3 = adj[p + 3];
        float v0 = X[(size_t)j0 * ldx + lane];
        float v1 = X[(size_t)j1 * ldx + lane];
        float v2 = X[(size_t)j2 * ldx + lane];
        float v3 = X[(size_t)j3 * ldx + lane];
        acc += (v0 + v1) + (v2 + v3);
        p += 4;
    }
    for (; p < e; p++) acc += X[(size_t)adj[p] * ldx + lane];
    AGG[(size_t)node * 64 + lane] = acc;
}

// ---------------- GEMM (N x 64) @ (64 x 64) + bias, fp32, + BN stats ----------
// block 256 = 16x16 threads; block tile 64 rows x 64 cols; 4x4 micro-tile/thread
__global__ void gemm64_k(const float* __restrict__ A,
                         const float* __restrict__ W,    // 64x64 row-major
                         const float* __restrict__ bias,
                         float* __restrict__ T,
                         float* __restrict__ sums) {  // [64] sum, [64] sumsq
    __shared__ float As[64 * 72];   // [k][r], pad 72
    __shared__ float Ws[64 * 64];   // [k][n]
    __shared__ float lsum[64], lssq[64];
    int tid = threadIdx.x;
    int rowbase = blockIdx.x * 64;
    // A: 64 rows x 16 float4 each
    for (int i = tid; i < 64 * 16; i += 256) {
        int r = i >> 4, kq = i & 15;
        int row = rowbase + r;
        if (row >= NN) row = NN - 1;
        f32x4 v = *(const f32x4*)(A + (size_t)row * 64 + kq * 4);
        #pragma unroll
        for (int q = 0; q < 4; q++) As[(kq * 4 + q) * 72 + r] = v[q];
    }
    // W: contiguous copy, 1024 float4
    for (int i = tid; i < 1024; i += 256) {
        *(f32x4*)(Ws + i * 4) = *(const f32x4*)(W + i * 4);
    }
    if (tid < 64) { lsum[tid] = 0.f; lssq[tid] = 0.f; }
    __syncthreads();

    int ty = tid >> 4, tx = tid & 15;
    float acc[4][4] = {};
    for (int k = 0; k < 64; k++) {
        float a[4], wv[4];
        #pragma unroll
        for (int i = 0; i < 4; i++) a[i] = As[k * 72 + ty * 4 + i];
        #pragma unroll
        for (int j = 0; j < 4; j++) wv[j] = Ws[k * 64 + tx * 4 + j];
        #pragma unroll
        for (int i = 0; i < 4; i++)
            #pragma unroll
            for (int j = 0; j < 4; j++) acc[i][j] += a[i] * wv[j];
    }

    f32x4 bv = *(const f32x4*)(bias + tx * 4);
    float ps[4] = {0.f, 0.f, 0.f, 0.f}, pq[4] = {0.f, 0.f, 0.f, 0.f};
    #pragma unroll
    for (int i = 0; i < 4; i++) {
        int row = rowbase + ty * 4 + i;
        if (row < NN) {
            f32x4 v;
            #pragma unroll
            for (int j = 0; j < 4; j++) {
                v[j] = acc[i][j] + bv[j];
                ps[j] += v[j];
                pq[j] += v[j] * v[j];
            }
            *(f32x4*)(T + (size_t)row * 64 + tx * 4) = v;
        }
    }
    #pragma unroll
    for (int j = 0; j < 4; j++) {
        atomicAdd(&lsum[tx * 4 + j], ps[j]);
        atomicAdd(&lssq[tx * 4 + j], pq[j]);
    }
    __syncthreads();
    if (tid < 64) {
        atomicAdd(&sums[tid], lsum[tid]);
        atomicAdd(&sums[64 + tid], lssq[tid]);
    }
}

// ---- GEMM with fused BN+ReLU on the input: A = relu(Tin*sc + sh), then @W ----
__global__ void gemm64bn_k(const float* __restrict__ Tin,
                           const float* __restrict__ stats,  // [64] sum,[64] sumsq of Tin
                           const float* __restrict__ g,
                           const float* __restrict__ be,
                           const float* __restrict__ W,      // 64x64 row-major
                           const float* __restrict__ bias,
                           float* __restrict__ T,
                           float* __restrict__ sums) {
    __shared__ float As[64 * 72];
    __shared__ float Ws[64 * 64];
    __shared__ float sc[64], sh[64];
    __shared__ float lsum[64], lssq[64];
    int tid = threadIdx.x;
    int rowbase = blockIdx.x * 64;
    if (tid < 64) {
        float m = stats[tid] * (1.0f / NN);
        float var = stats[64 + tid] * (1.0f / NN) - m * m;
        if (var < 0.f) var = 0.f;
        float s = g[tid] * rsqrtf(var + BN_EPS);
        sc[tid] = s;
        sh[tid] = be[tid] - m * s;
        lsum[tid] = 0.f;
        lssq[tid] = 0.f;
    }
    __syncthreads();
    for (int i = tid; i < 64 * 16; i += 256) {
        int r = i >> 4, kq = i & 15;
        int row = rowbase + r;
        if (row >= NN) row = NN - 1;
        f32x4 v = *(const f32x4*)(Tin + (size_t)row * 64 + kq * 4);
        #pragma unroll
        for (int q = 0; q < 4; q++) {
            int k = kq * 4 + q;
            float u = v[q] * sc[k] + sh[k];
            As[k * 72 + r] = u > 0.f ? u : 0.f;
        }
    }
    for (int i = tid; i < 1024; i += 256) {
        *(f32x4*)(Ws + i * 4) = *(const f32x4*)(W + i * 4);
    }
    __syncthreads();

    int ty = tid >> 4, tx = tid & 15;
    float acc[4][4] = {};
    for (int k = 0; k < 64; k++) {
        float a[4], wv[4];
        #pragma unroll
        for (int i = 0; i < 4; i++) a[i] = As[k * 72 + ty * 4 + i];
        #pragma unroll
        for (int j = 0; j < 4; j++) wv[j] = Ws[k * 64 + tx * 4 + j];
        #pragma unroll
        for (int i = 0; i < 4; i++)
            #pragma unroll
            for (int j = 0; j < 4; j++) acc[i][j] += a[i] * wv[j];
    }

    f32x4 bv = *(const f32x4*)(bias + tx * 4);
    float ps[4] = {0.f, 0.f, 0.f, 0.f}, pq[4] = {0.f, 0.f, 0.f, 0.f};
    #pragma unroll
    for (int i = 0; i < 4; i++) {
        int row = rowbase + ty * 4 + i;
        if (row < NN) {
            f32x4 v;
            #pragma unroll
            for (int j = 0; j < 4; j++) {
                v[j] = acc[i][j] + bv[j];
                ps[j] += v[j];
                pq[j] += v[j] * v[j];
            }
            *(f32x4*)(T + (size_t)row * 64 + tx * 4) = v;
        }
    }
    #pragma unroll
    for (int j = 0; j < 4; j++) {
        atomicAdd(&lsum[tx * 4 + j], ps[j]);
        atomicAdd(&lssq[tx * 4 + j], pq[j]);
    }
    __syncthreads();
    if (tid < 64) {
        atomicAdd(&sums[tid], lsum[tid]);
        atomicAdd(&sums[64 + tid], lssq[tid]);
    }
}

// ---------------- BN finalize + apply + ReLU (fp32), strided output ------------
__global__ void bn_k(const float* __restrict__ T, const float* __restrict__ sums,
                     const float* __restrict__ g,
                     const float* __restrict__ be,
                     float* __restrict__ H, int ldh) {
    __shared__ float sc[64], sh[64];
    int tid = threadIdx.x;
    if (tid < 64) {
        float m = sums[tid] * (1.0f / NN);
        float var = sums[64 + tid] * (1.0f / NN) - m * m;
        if (var < 0.f) var = 0.f;
        float s = g[tid] * rsqrtf(var + BN_EPS);
        sc[tid] = s;
        sh[tid] = be[tid] - m * s;
    }
    __syncthreads();
    int i = blockIdx.x * 256 + tid;  // over NN*16 float4s
    if (i < NN * 16) {
        int row = i >> 4, f = (i & 15) * 4;
        f32x4 v = *(const f32x4*)(T + (size_t)row * 64 + f);
        f32x4 u;
        #pragma unroll
        for (int j = 0; j < 4; j++) {
            float w = v[j] * sc[f + j] + sh[f + j];
            u[j] = w > 0.f ? w : 0.f;
        }
        *(f32x4*)(H + (size_t)row * ldh + f) = u;
    }
}

// ---------------- final GEMM: (N x 128) @ (128 x 64) + bias -> fp32 out -------
__global__ void gemmfin_k(const float* __restrict__ A,   // N x 128 fp32
                          const float* __restrict__ W,   // 128x64 row-major
                          const float* __restrict__ bias,
                          float* __restrict__ O) {
    __shared__ float As[128 * 72];
    __shared__ float Ws[128 * 64];
    int tid = threadIdx.x;
    int rowbase = blockIdx.x * 64;
    for (int i = tid; i < 64 * 32; i += 256) {
        int r = i >> 5, kq = i & 31;
        int row = rowbase + r;
        if (row >= NN) row = NN - 1;
        f32x4 v = *(const f32x4*)(A + (size_t)row * 128 + kq * 4);
        #pragma unroll
        for (int q = 0; q < 4; q++) As[(kq * 4 + q) * 72 + r] = v[q];
    }
    for (int i = tid; i < 2048; i += 256) {
        *(f32x4*)(Ws + i * 4) = *(const f32x4*)(W + i * 4);
    }
    __syncthreads();

    int ty = tid >> 4, tx = tid & 15;
    float acc[4][4] = {};
    for (int k = 0; k < 128; k++) {
        float a[4], wv[4];
        #pragma unroll
        for (int i = 0; i < 4; i++) a[i] = As[k * 72 + ty * 4 + i];
        #pragma unroll
        for (int j = 0; j < 4; j++) wv[j] = Ws[k * 64 + tx * 4 + j];
        #pragma unroll
        for (int i = 0; i < 4; i++)
            #pragma unroll
            for (int j = 0; j < 4; j++) acc[i][j] += a[i] * wv[j];
    }

    f32x4 bv = *(const f32x4*)(bias + tx * 4);
    #pragma unroll
    for (int i = 0; i < 4; i++) {
        int row = rowbase + ty * 4 + i;
        if (row < NN) {
            f32x4 v;
            #pragma unroll
            for (int j = 0; j < 4; j++) v[j] = acc[i][j] + bv[j];
            *(f32x4*)(O + (size_t)row * 64 + tx * 4) = v;
        }
    }
}

// ---------------- launch ----------------
extern "C" void kernel_launch(void* const* d_in, const int* in_sizes, int n_in,
                              void* d_out, int out_size, void* d_ws, size_t ws_size,
                              hipStream_t stream) {
    const float* x   = (const float*)d_in[0];
    const int*   ei  = (const int*)d_in[1];
    const float* w0a = (const float*)d_in[2];
    const float* b0a = (const float*)d_in[3];
    const float* g0a = (const float*)d_in[4];
    const float* be0a= (const float*)d_in[5];
    const float* w0b = (const float*)d_in[6];
    const float* b0b = (const float*)d_in[7];
    const float* g0b = (const float*)d_in[8];
    const float* be0b= (const float*)d_in[9];
    const float* w1a = (const float*)d_in[10];
    const float* b1a = (const float*)d_in[11];
    const float* g1a = (const float*)d_in[12];
    const float* be1a= (const float*)d_in[13];
    const float* w1b = (const float*)d_in[14];
    const float* b1b = (const float*)d_in[15];
    const float* g1b = (const float*)d_in[16];
    const float* be1b= (const float*)d_in[17];
    const float* lw  = (const float*)d_in[18];
    const float* lb  = (const float*)d_in[19];
    float* out = (float*)d_out;
    (void)in_sizes; (void)n_in; (void)out_size; (void)ws_size;

    char* wsb = (char*)d_ws;
    size_t o = 0;
    auto alloc = [&](size_t bytes) -> char* {
        char* p = wsb + o;
        o += (bytes + 255) & ~(size_t)255;
        return p;
    };
    int* deg = (int*)alloc(NN * 4);           // zeroed below
    float* sums = (float*)alloc(512 * 4);     // zeroed below (4 sets of 128)
    int* part = (int*)alloc(SCAN_BLKS * 4);
    int* blkoff = (int*)alloc(SCAN_BLKS * 4);
    int* off = (int*)alloc((NN + 1) * 4);
    int* cur = (int*)alloc(NN * 4);
    int* adj = (int*)alloc(NE * 4);
    float* AGG = (float*)alloc((size_t)NN * 64 * 4);
    float* T   = (float*)alloc((size_t)NN * 64 * 4);
    float* T2  = (float*)alloc((size_t)NN * 64 * 4);
    float* HC  = (float*)alloc((size_t)NN * 128 * 4);

    const int* src = ei;
    const int* dst = ei + NE;

    // zero deg (padded to 200192 B) + sums (2048 B) = 50560 ints
    zero_k<<<198, 256, 0, stream>>>((int*)d_ws, 50560);
    hist_k<<<NE / 256, 256, 0, stream>>>(dst, deg);
    blocksum_k<<<SCAN_BLKS, 256, 0, stream>>>(deg, part);
    scanpart_k<<<1, 256, 0, stream>>>(part, blkoff, off);
    applyscan_k<<<SCAN_BLKS, 256, 0, stream>>>(deg, blkoff, off, cur);
    scatter_k<<<NE / 256, 256, 0, stream>>>(src, dst, cur, adj);

    const int ggrid = NN / 4;                  // 12500 (wave per node)
    const int mgrid = (NN + 63) / 64;          // 782
    const int agrid = (NN * 16 + 255) / 256;   // 3125 (float4 granularity)

    // ---- layer 0 ----
    gather_k<<<ggrid, 256, 0, stream>>>(x, 64, off, adj, AGG);
    gemm64_k<<<mgrid, 256, 0, stream>>>(AGG, w0a, b0a, T, sums + 0);
    gemm64bn_k<<<mgrid, 256, 0, stream>>>(T, sums + 0, g0a, be0a, w0b, b0b, T2, sums + 128);
    bn_k<<<agrid, 256, 0, stream>>>(T2, sums + 128, g0b, be0b, HC, 128);      // h1

    // ---- layer 1 ----
    gather_k<<<ggrid, 256, 0, stream>>>(HC, 128, off, adj, AGG);
    gemm64_k<<<mgrid, 256, 0, stream>>>(AGG, w1a, b1a, T, sums + 256);
    gemm64bn_k<<<mgrid, 256, 0, stream>>>(T, sums + 256, g1a, be1a, w1b, b1b, T2, sums + 384);
    bn_k<<<agrid, 256, 0, stream>>>(T2, sums + 384, g1b, be1b, HC + 64, 128); // h2

    // ---- JK cat + final linear ----
    gemmfin_k<<<mgrid, 256, 0, stream>>>(HC, lw, lb, out);
}

// Round 6
// 370.323 us; speedup vs baseline: 1.7550x; 1.1361x over previous
//
#include <hip/hip_runtime.h>
#include <hip/hip_bf16.h>

#define NN 50000
#define NE 800000
#define BN_EPS 1e-5f
#define CHUNK 8192
#define NCH 98     // ceil(NE / CHUNK)
#define NBK 196    // ceil(NN / 256) dst-buckets

typedef __attribute__((ext_vector_type(4))) float f32x4;

// ---------------- utility: zero ints (bcnt + sums) ----------------
__global__ void zero_k(int* __restrict__ p, int n) {
    int i = blockIdx.x * 256 + threadIdx.x;
    if (i < n) p[i] = 0;
}

// ---------------- bucket histogram: bucket = dst >> 8 ----------------
__global__ void bhist_k(const int* __restrict__ dst, int* __restrict__ bcnt) {
    __shared__ int c[256];
    int t = threadIdx.x;
    c[t] = 0;
    __syncthreads();
    int base = blockIdx.x * CHUNK;
    int n = NE - base; if (n > CHUNK) n = CHUNK;
    for (int i = t; i < n; i += 256) atomicAdd(&c[dst[base + i] >> 8], 1);
    __syncthreads();
    if (c[t]) atomicAdd(&bcnt[t], c[t]);
}

// ---------------- scan bucket counts -> bbase/bres ----------------
__global__ void bscan_k(const int* __restrict__ bcnt, int* __restrict__ bbase,
                        int* __restrict__ bres, int* __restrict__ off) {
    __shared__ int s[256];
    int t = threadIdx.x;
    int v = bcnt[t];
    s[t] = v;
    __syncthreads();
    for (int d = 1; d < 256; d <<= 1) {
        int u = (t >= d) ? s[t - d] : 0;
        __syncthreads();
        s[t] += u;
        __syncthreads();
    }
    int ex = s[t] - v;
    bbase[t] = ex;
    bres[t] = ex;
    if (t == 0) { bbase[256] = NE; off[NN] = NE; }
}

// ---------------- bucket scatter: chunk -> bucket-ordered global ebuf ---------
// packed int: src (16b) | dst&255 (8b) | bucket (8b)
__global__ void bscatter_k(const int* __restrict__ src, const int* __restrict__ dst,
                           int* __restrict__ bres, int* __restrict__ ebuf) {
    __shared__ int cnt[256], loff[256], lcur[256], gst[256], sc[256];
    __shared__ int packed[CHUNK];
    int t = threadIdx.x;
    cnt[t] = 0;
    __syncthreads();
    int base = blockIdx.x * CHUNK;
    int n = NE - base; if (n > CHUNK) n = CHUNK;
    for (int i = t; i < n; i += 256) atomicAdd(&cnt[dst[base + i] >> 8], 1);
    __syncthreads();
    sc[t] = cnt[t];
    __syncthreads();
    for (int d = 1; d < 256; d <<= 1) {
        int u = (t >= d) ? sc[t - d] : 0;
        __syncthreads();
        sc[t] += u;
        __syncthreads();
    }
    loff[t] = sc[t] - cnt[t];
    lcur[t] = loff[t];
    __syncthreads();
    for (int i = t; i < n; i += 256) {
        int d = dst[base + i];
        int b = d >> 8;
        int p = atomicAdd(&lcur[b], 1);
        packed[p] = src[base + i] | ((d & 255) << 16) | (b << 24);
    }
    __syncthreads();
    if (cnt[t]) gst[t] = atomicAdd(&bres[t], cnt[t]);
    __syncthreads();
    for (int i = t; i < n; i += 256) {
        int v = packed[i];
        int b = (v >> 24) & 255;
        ebuf[gst[b] + i - loff[b]] = v & 0xFFFFFF;
    }
}

// ---------------- per-bucket CSR: off[] + adj[] (all writes XCD-local) --------
__global__ void csr_k(const int* __restrict__ bbase, const int* __restrict__ ebuf,
                      int* __restrict__ off, int* __restrict__ adj) {
    __shared__ int cnt[256], loff[256], lcur[256], sc[256];
    int b = blockIdx.x, t = threadIdx.x;
    int s0 = bbase[b], s1 = bbase[b + 1];
    int n = s1 - s0;
    cnt[t] = 0;
    __syncthreads();
    for (int i = t; i < n; i += 256) atomicAdd(&cnt[(ebuf[s0 + i] >> 16) & 255], 1);
    __syncthreads();
    sc[t] = cnt[t];
    __syncthreads();
    for (int d = 1; d < 256; d <<= 1) {
        int u = (t >= d) ? sc[t - d] : 0;
        __syncthreads();
        sc[t] += u;
        __syncthreads();
    }
    loff[t] = sc[t] - cnt[t];
    lcur[t] = loff[t];
    int node = b * 256 + t;
    if (node < NN) off[node] = s0 + loff[t];
    __syncthreads();
    for (int i = t; i < n; i += 256) {
        int v = ebuf[s0 + i];
        int p = atomicAdd(&lcur[(v >> 16) & 255], 1);
        adj[s0 + p] = v & 0xFFFF;
    }
}

// ---------------- aggregation: AGG[i] = X[i] + sum_{j->i} X[j]  (fp32) ---------
// one wave per node, lane = feature (64 feats); 8-deep load pipelining
__global__ void gather_k(const float* __restrict__ X, int ldx,
                         const int* __restrict__ off, const int* __restrict__ adj,
                         float* __restrict__ AGG) {
    int node = blockIdx.x * 4 + (threadIdx.x >> 6);
    int lane = threadIdx.x & 63;
    if (node >= NN) return;
    float acc = X[(size_t)node * ldx + lane];
    int s = off[node], e = off[node + 1];
    int p = s;
    for (; p + 8 <= e; p += 8) {
        int j0 = adj[p + 0], j1 = adj[p + 1], j2 = adj[p + 2], j3 = adj[p + 3];
        int j4 = adj[p + 4], j5 = adj[p + 5], j6 = adj[p + 6], j7 = adj[p + 7];
        float v0 = X[(size_t)j0 * ldx + lane];
        float v1 = X[(size_t)j1 * ldx + lane];
        float v2 = X[(size_t)j2 * ldx + lane];
        float v3 = X[(size_t)j3 * ldx + lane];
        float v4 = X[(size_t)j4 * ldx + lane];
        float v5 = X[(size_t)j5 * ldx + lane];
        float v6 = X[(size_t)j6 * ldx + lane];
        float v7 = X[(size_t)j7 * ldx + lane];
        acc += ((v0 + v1) + (v2 + v3)) + ((v4 + v5) + (v6 + v7));
    }
    if (p + 4 <= e) {
        int j0 = adj[p + 0], j1 = adj[p + 1], j2 = adj[p + 2], j3 = adj[p + 3];
        float v0 = X[(size_t)j0 * ldx + lane];
        float v1 = X[(size_t)j1 * ldx + lane];
        float v2 = X[(size_t)j2 * ldx + lane];
        float v3 = X[(size_t)j3 * ldx + lane];
        acc += (v0 + v1) + (v2 + v3);
        p += 4;
    }
    for (; p < e; p++) acc += X[(size_t)adj[p] * ldx + lane];
    AGG[(size_t)node * 64 + lane] = acc;
}

// ---------------- GEMM (N x 64) @ (64 x 64) + bias, fp32, + BN stats ----------
__global__ void gemm64_k(const float* __restrict__ A,
                         const float* __restrict__ W,    // 64x64 row-major
                         const float* __restrict__ bias,
                         float* __restrict__ T,
                         float* __restrict__ sums) {  // [64] sum, [64] sumsq
    __shared__ float As[64 * 72];   // [k][r], pad 72
    __shared__ float Ws[64 * 64];   // [k][n]
    __shared__ float lsum[64], lssq[64];
    int tid = threadIdx.x;
    int rowbase = blockIdx.x * 64;
    for (int i = tid; i < 64 * 16; i += 256) {
        int r = i >> 4, kq = i & 15;
        int row = rowbase + r;
        if (row >= NN) row = NN - 1;
        f32x4 v = *(const f32x4*)(A + (size_t)row * 64 + kq * 4);
        #pragma unroll
        for (int q = 0; q < 4; q++) As[(kq * 4 + q) * 72 + r] = v[q];
    }
    for (int i = tid; i < 1024; i += 256) {
        *(f32x4*)(Ws + i * 4) = *(const f32x4*)(W + i * 4);
    }
    if (tid < 64) { lsum[tid] = 0.f; lssq[tid] = 0.f; }
    __syncthreads();

    int ty = tid >> 4, tx = tid & 15;
    float acc[4][4] = {};
    for (int k = 0; k < 64; k++) {
        float a[4], wv[4];
        #pragma unroll
        for (int i = 0; i < 4; i++) a[i] = As[k * 72 + ty * 4 + i];
        #pragma unroll
        for (int j = 0; j < 4; j++) wv[j] = Ws[k * 64 + tx * 4 + j];
        #pragma unroll
        for (int i = 0; i < 4; i++)
            #pragma unroll
            for (int j = 0; j < 4; j++) acc[i][j] += a[i] * wv[j];
    }

    f32x4 bv = *(const f32x4*)(bias + tx * 4);
    float ps[4] = {0.f, 0.f, 0.f, 0.f}, pq[4] = {0.f, 0.f, 0.f, 0.f};
    #pragma unroll
    for (int i = 0; i < 4; i++) {
        int row = rowbase + ty * 4 + i;
        if (row < NN) {
            f32x4 v;
            #pragma unroll
            for (int j = 0; j < 4; j++) {
                v[j] = acc[i][j] + bv[j];
                ps[j] += v[j];
                pq[j] += v[j] * v[j];
            }
            *(f32x4*)(T + (size_t)row * 64 + tx * 4) = v;
        }
    }
    #pragma unroll
    for (int j = 0; j < 4; j++) {
        atomicAdd(&lsum[tx * 4 + j], ps[j]);
        atomicAdd(&lssq[tx * 4 + j], pq[j]);
    }
    __syncthreads();
    if (tid < 64) {
        atomicAdd(&sums[tid], lsum[tid]);
        atomicAdd(&sums[64 + tid], lssq[tid]);
    }
}

// ---- GEMM with fused BN+ReLU on the input: A = relu(Tin*sc + sh), then @W ----
__global__ void gemm64bn_k(const float* __restrict__ Tin,
                           const float* __restrict__ stats,  // [64] sum,[64] sumsq of Tin
                           const float* __restrict__ g,
                           const float* __restrict__ be,
                           const float* __restrict__ W,      // 64x64 row-major
                           const float* __restrict__ bias,
                           float* __restrict__ T,
                           float* __restrict__ sums) {
    __shared__ float As[64 * 72];
    __shared__ float Ws[64 * 64];
    __shared__ float sc[64], sh[64];
    __shared__ float lsum[64], lssq[64];
    int tid = threadIdx.x;
    int rowbase = blockIdx.x * 64;
    if (tid < 64) {
        float m = stats[tid] * (1.0f / NN);
        float var = stats[64 + tid] * (1.0f / NN) - m * m;
        if (var < 0.f) var = 0.f;
        float s = g[tid] * rsqrtf(var + BN_EPS);
        sc[tid] = s;
        sh[tid] = be[tid] - m * s;
        lsum[tid] = 0.f;
        lssq[tid] = 0.f;
    }
    __syncthreads();
    for (int i = tid; i < 64 * 16; i += 256) {
        int r = i >> 4, kq = i & 15;
        int row = rowbase + r;
        if (row >= NN) row = NN - 1;
        f32x4 v = *(const f32x4*)(Tin + (size_t)row * 64 + kq * 4);
        #pragma unroll
        for (int q = 0; q < 4; q++) {
            int k = kq * 4 + q;
            float u = v[q] * sc[k] + sh[k];
            As[k * 72 + r] = u > 0.f ? u : 0.f;
        }
    }
    for (int i = tid; i < 1024; i += 256) {
        *(f32x4*)(Ws + i * 4) = *(const f32x4*)(W + i * 4);
    }
    __syncthreads();

    int ty = tid >> 4, tx = tid & 15;
    float acc[4][4] = {};
    for (int k = 0; k < 64; k++) {
        float a[4], wv[4];
        #pragma unroll
        for (int i = 0; i < 4; i++) a[i] = As[k * 72 + ty * 4 + i];
        #pragma unroll
        for (int j = 0; j < 4; j++) wv[j] = Ws[k * 64 + tx * 4 + j];
        #pragma unroll
        for (int i = 0; i < 4; i++)
            #pragma unroll
            for (int j = 0; j < 4; j++) acc[i][j] += a[i] * wv[j];
    }

    f32x4 bv = *(const f32x4*)(bias + tx * 4);
    float ps[4] = {0.f, 0.f, 0.f, 0.f}, pq[4] = {0.f, 0.f, 0.f, 0.f};
    #pragma unroll
    for (int i = 0; i < 4; i++) {
        int row = rowbase + ty * 4 + i;
        if (row < NN) {
            f32x4 v;
            #pragma unroll
            for (int j = 0; j < 4; j++) {
                v[j] = acc[i][j] + bv[j];
                ps[j] += v[j];
                pq[j] += v[j] * v[j];
            }
            *(f32x4*)(T + (size_t)row * 64 + tx * 4) = v;
        }
    }
    #pragma unroll
    for (int j = 0; j < 4; j++) {
        atomicAdd(&lsum[tx * 4 + j], ps[j]);
        atomicAdd(&lssq[tx * 4 + j], pq[j]);
    }
    __syncthreads();
    if (tid < 64) {
        atomicAdd(&sums[tid], lsum[tid]);
        atomicAdd(&sums[64 + tid], lssq[tid]);
    }
}

// ---------------- BN finalize + apply + ReLU (fp32), strided output ------------
__global__ void bn_k(const float* __restrict__ T, const float* __restrict__ sums,
                     const float* __restrict__ g,
                     const float* __restrict__ be,
                     float* __restrict__ H, int ldh) {
    __shared__ float sc[64], sh[64];
    int tid = threadIdx.x;
    if (tid < 64) {
        float m = sums[tid] * (1.0f / NN);
        float var = sums[64 + tid] * (1.0f / NN) - m * m;
        if (var < 0.f) var = 0.f;
        float s = g[tid] * rsqrtf(var + BN_EPS);
        sc[tid] = s;
        sh[tid] = be[tid] - m * s;
    }
    __syncthreads();
    int i = blockIdx.x * 256 + tid;  // over NN*16 float4s
    if (i < NN * 16) {
        int row = i >> 4, f = (i & 15) * 4;
        f32x4 v = *(const f32x4*)(T + (size_t)row * 64 + f);
        f32x4 u;
        #pragma unroll
        for (int j = 0; j < 4; j++) {
            float w = v[j] * sc[f + j] + sh[f + j];
            u[j] = w > 0.f ? w : 0.f;
        }
        *(f32x4*)(H + (size_t)row * ldh + f) = u;
    }
}

// ---------------- final GEMM: (N x 128) @ (128 x 64) + bias -> fp32 out -------
__global__ void gemmfin_k(const float* __restrict__ A,   // N x 128 fp32
                          const float* __restrict__ W,   // 128x64 row-major
                          const float* __restrict__ bias,
                          float* __restrict__ O) {
    __shared__ float As[128 * 72];
    __shared__ float Ws[128 * 64];
    int tid = threadIdx.x;
    int rowbase = blockIdx.x * 64;
    for (int i = tid; i < 64 * 32; i += 256) {
        int r = i >> 5, kq = i & 31;
        int row = rowbase + r;
        if (row >= NN) row = NN - 1;
        f32x4 v = *(const f32x4*)(A + (size_t)row * 128 + kq * 4);
        #pragma unroll
        for (int q = 0; q < 4; q++) As[(kq * 4 + q) * 72 + r] = v[q];
    }
    for (int i = tid; i < 2048; i += 256) {
        *(f32x4*)(Ws + i * 4) = *(const f32x4*)(W + i * 4);
    }
    __syncthreads();

    int ty = tid >> 4, tx = tid & 15;
    float acc[4][4] = {};
    for (int k = 0; k < 128; k++) {
        float a[4], wv[4];
        #pragma unroll
        for (int i = 0; i < 4; i++) a[i] = As[k * 72 + ty * 4 + i];
        #pragma unroll
        for (int j = 0; j < 4; j++) wv[j] = Ws[k * 64 + tx * 4 + j];
        #pragma unroll
        for (int i = 0; i < 4; i++)
            #pragma unroll
            for (int j = 0; j < 4; j++) acc[i][j] += a[i] * wv[j];
    }

    f32x4 bv = *(const f32x4*)(bias + tx * 4);
    #pragma unroll
    for (int i = 0; i < 4; i++) {
        int row = rowbase + ty * 4 + i;
        if (row < NN) {
            f32x4 v;
            #pragma unroll
            for (int j = 0; j < 4; j++) v[j] = acc[i][j] + bv[j];
            *(f32x4*)(O + (size_t)row * 64 + tx * 4) = v;
        }
    }
}

// ---------------- launch ----------------
extern "C" void kernel_launch(void* const* d_in, const int* in_sizes, int n_in,
                              void* d_out, int out_size, void* d_ws, size_t ws_size,
                              hipStream_t stream) {
    const float* x   = (const float*)d_in[0];
    const int*   ei  = (const int*)d_in[1];
    const float* w0a = (const float*)d_in[2];
    const float* b0a = (const float*)d_in[3];
    const float* g0a = (const float*)d_in[4];
    const float* be0a= (const float*)d_in[5];
    const float* w0b = (const float*)d_in[6];
    const float* b0b = (const float*)d_in[7];
    const float* g0b = (const float*)d_in[8];
    const float* be0b= (const float*)d_in[9];
    const float* w1a = (const float*)d_in[10];
    const float* b1a = (const float*)d_in[11];
    const float* g1a = (const float*)d_in[12];
    const float* be1a= (const float*)d_in[13];
    const float* w1b = (const float*)d_in[14];
    const float* b1b = (const float*)d_in[15];
    const float* g1b = (const float*)d_in[16];
    const float* be1b= (const float*)d_in[17];
    const float* lw  = (const float*)d_in[18];
    const float* lb  = (const float*)d_in[19];
    float* out = (float*)d_out;
    (void)in_sizes; (void)n_in; (void)out_size; (void)ws_size;

    char* wsb = (char*)d_ws;
    size_t o = 0;
    auto alloc = [&](size_t bytes) -> char* {
        char* p = wsb + o;
        o += (bytes + 255) & ~(size_t)255;
        return p;
    };
    int* bcnt = (int*)alloc(256 * 4);         // zeroed below (pads to 1024B)
    float* sums = (float*)alloc(512 * 4);     // zeroed below (4 sets of 128)
    int* bbase = (int*)alloc(257 * 4);
    int* bres = (int*)alloc(256 * 4);
    int* off = (int*)alloc((NN + 1) * 4);
    int* adj = (int*)alloc(NE * 4);
    int* ebuf = (int*)alloc(NE * 4);
    float* AGG = (float*)alloc((size_t)NN * 64 * 4);
    float* T   = (float*)alloc((size_t)NN * 64 * 4);
    float* T2  = (float*)alloc((size_t)NN * 64 * 4);
    float* HC  = (float*)alloc((size_t)NN * 128 * 4);

    const int* src = ei;
    const int* dst = ei + NE;

    // zero bcnt (1024 B) + sums (2048 B) = 768 ints contiguous
    zero_k<<<3, 256, 0, stream>>>((int*)d_ws, 768);
    bhist_k<<<NCH, 256, 0, stream>>>(dst, bcnt);
    bscan_k<<<1, 256, 0, stream>>>(bcnt, bbase, bres, off);
    bscatter_k<<<NCH, 256, 0, stream>>>(src, dst, bres, ebuf);
    csr_k<<<NBK, 256, 0, stream>>>(bbase, ebuf, off, adj);

    const int ggrid = NN / 4;                  // 12500 (wave per node)
    const int mgrid = (NN + 63) / 64;          // 782
    const int agrid = (NN * 16 + 255) / 256;   // 3125 (float4 granularity)

    // ---- layer 0 ----
    gather_k<<<ggrid, 256, 0, stream>>>(x, 64, off, adj, AGG);
    gemm64_k<<<mgrid, 256, 0, stream>>>(AGG, w0a, b0a, T, sums + 0);
    gemm64bn_k<<<mgrid, 256, 0, stream>>>(T, sums + 0, g0a, be0a, w0b, b0b, T2, sums + 128);
    bn_k<<<agrid, 256, 0, stream>>>(T2, sums + 128, g0b, be0b, HC, 128);      // h1

    // ---- layer 1 ----
    gather_k<<<ggrid, 256, 0, stream>>>(HC, 128, off, adj, AGG);
    gemm64_k<<<mgrid, 256, 0, stream>>>(AGG, w1a, b1a, T, sums + 256);
    gemm64bn_k<<<mgrid, 256, 0, stream>>>(T, sums + 256, g1a, be1a, w1b, b1b, T2, sums + 384);
    bn_k<<<agrid, 256, 0, stream>>>(T2, sums + 384, g1b, be1b, HC + 64, 128); // h2

    // ---- JK cat + final linear ----
    gemmfin_k<<<mgrid, 256, 0, stream>>>(HC, lw, lb, out);
}